// Round 7
// baseline (264.140 us; speedup 1.0000x reference)
//
#include <hip/hip_runtime.h>

// ---------- types ----------
typedef float f32x4 __attribute__((ext_vector_type(4)));
typedef float f32x16 __attribute__((ext_vector_type(16)));
typedef __bf16 bf16x8 __attribute__((ext_vector_type(8)));

// ---------- bf16 helpers (RNE) ----------
__device__ __forceinline__ short f2bf(float f) {
    union { float f; unsigned u; } x; x.f = f;
    unsigned r = x.u + 0x7fffu + ((x.u >> 16) & 1u);
    return (short)(r >> 16);
}

__device__ __forceinline__ void store_out(float* p, float v) { *p = v; }
__device__ __forceinline__ void store_out(short* p, float v) { *p = f2bf(v); }

// async global->LDS, 16B per lane; lds dest = wave-uniform base (HW adds lane*16)
__device__ __forceinline__ void gload_lds16(const short* g, short* l) {
    __builtin_amdgcn_global_load_lds(
        (__attribute__((address_space(1))) void*)(void*)g,
        (__attribute__((address_space(3))) void*)l, 16, 0, 0);
}

// ---------- prep: x->bf16 cvt + Wq/Wkv transposes (qkv GEMM's inputs only) ----
__global__ void prep_all(const float* __restrict__ x, short* __restrict__ xb,
                         const float* __restrict__ Wq, const float* __restrict__ Wkv,
                         short* __restrict__ WqkvT) {
    __shared__ float tile[32][33];
    int id = blockIdx.x;
    const int t = threadIdx.x;
    if (id < 8192) {
        const int i = id * 256 + t;
        float4 v = ((const float4*)x)[i];
        ((short4*)xb)[i] = make_short4(f2bf(v.x), f2bf(v.y), f2bf(v.z), f2bf(v.w));
        return;
    }
    id -= 8192;
    const float* in; short* out; int R, C, xt, yt;
    if (id < 4096) { in = Wq;  out = WqkvT; R = 2048; C = 2048; xt = id & 63; yt = id >> 6; }
    else           { id -= 4096; in = Wkv; out = WqkvT + (size_t)2048 * 2048;
                     R = 2048; C = 512; xt = id & 15; yt = id >> 4; }
    const int c0 = xt * 32, r0 = yt * 32;
    const int tx = t & 31, ty = t >> 5;
#pragma unroll
    for (int i = 0; i < 32; i += 8)
        tile[ty + i][tx] = in[(size_t)(r0 + ty + i) * C + c0 + tx];
    __syncthreads();
#pragma unroll
    for (int i = 0; i < 32; i += 8)
        out[(size_t)(c0 + ty + i) * R + r0 + tx] = f2bf(tile[tx][ty + i]);
}

// ============================================================================
// 128x128 2-phase bf16 GEMM core (m97-structure). Used by the qkv dispatch.
// ============================================================================
template <typename OutT>
__device__ __forceinline__ void gemm32_core(
    const short* __restrict__ A, const short* __restrict__ Bt, OutT* __restrict__ C,
    int m0, int n0, int K, int lda, int ldb, int ldc, short* sA, short* sB) {
    const int t = threadIdx.x;
    const int w = t >> 6, l = t & 63;
    const int wr = w >> 1, wc = w & 1;
    const int lrow = l & 31, lhalf = l >> 5;

    f32x16 acc[2][2] = {};

    const int r_off = w * 32 + (l >> 3);
    const int c8 = (((l & 7) ^ (l >> 3)) & 7) * 8;
    const short* aB = A + (size_t)(m0 + r_off) * lda + c8;
    const short* bB = Bt + (size_t)(n0 + r_off) * ldb + c8;
    short* sAw = sA + w * 2048;
    short* sBw = sB + w * 2048;

    for (int kk = 0; kk < K; kk += 64) {
#pragma unroll
        for (int p = 0; p < 4; ++p) {
            gload_lds16(aB + kk + (size_t)(p * 8) * lda, sAw + p * 512);
            gload_lds16(bB + kk + (size_t)(p * 8) * ldb, sBw + p * 512);
        }
        __syncthreads();
#pragma unroll
        for (int ks = 0; ks < 4; ++ks) {
            const int c = ks * 2 + lhalf;   // k-chunk: k = ks*16 + lhalf*8 + j
            bf16x8 af[2], bfr[2];
#pragma unroll
            for (int mi = 0; mi < 2; ++mi) {
                const int m = wr * 64 + mi * 32 + lrow;
                af[mi] = *(const bf16x8*)&sA[m * 64 + (c ^ (m & 7)) * 8];
            }
#pragma unroll
            for (int ni = 0; ni < 2; ++ni) {
                const int n = wc * 64 + ni * 32 + lrow;
                bfr[ni] = *(const bf16x8*)&sB[n * 64 + (c ^ (n & 7)) * 8];
            }
#pragma unroll
            for (int mi = 0; mi < 2; ++mi)
#pragma unroll
                for (int ni = 0; ni < 2; ++ni)
                    acc[mi][ni] = __builtin_amdgcn_mfma_f32_32x32x16_bf16(
                        af[mi], bfr[ni], acc[mi][ni], 0, 0, 0);
        }
        __syncthreads();
    }
    // epilogue: C/D 32x32 layout: col = lane&31, row = (reg&3) + 8*(reg>>2) + 4*(lane>>5)
#pragma unroll
    for (int mi = 0; mi < 2; ++mi)
#pragma unroll
        for (int ni = 0; ni < 2; ++ni) {
            const int col = n0 + wc * 64 + ni * 32 + lrow;
#pragma unroll
            for (int r = 0; r < 16; ++r) {
                const int row = m0 + wr * 64 + mi * 32 + (r & 3) + 8 * (r >> 2) + 4 * lhalf;
                store_out(&C[(size_t)row * ldc + col], acc[mi][ni][r]);
            }
        }
}

// qkv GEMM (640 blocks, IDs first) + Wo/Wk/Wv transposes (6144 trailing blocks).
// ROUND-7: XCD-chunked bijective swizzle on the 640 GEMM blocks (640 = 8*80):
// XCD k gets contiguous logical tiles [80k, 80k+80) = 4 A-row-panels x 20 n —
// each 0.5 MB A-panel is read 20x from XCD-LOCAL L2 instead of re-fetched
// cross-die (staging-traffic-bound regime, T1 mechanism).
__global__ __launch_bounds__(256, 2)
void gemm32qkv(const short* __restrict__ A, const short* __restrict__ Bt,
               short* __restrict__ C,
               const float* __restrict__ Wo, const float* __restrict__ Wk,
               const float* __restrict__ Wv,
               short* __restrict__ WoT, short* __restrict__ WkT,
               short* __restrict__ WvT) {
    __shared__ __align__(16) short sA[128 * 64];
    __shared__ __align__(16) short sB[128 * 64];
    int id = blockIdx.x;
    if (id < 640) {
        // consecutive blockIdx -> XCD round-robin; chunk 80 logical tiles/XCD
        const int sw = (id & 7) * 80 + (id >> 3);
        // qkv: [4096][2560] = xb[4096][2048] * WqkvT[2560][2048]^T
        gemm32_core<short>(A, Bt, C, (sw / 20) * 128, (sw % 20) * 128,
                           2048, 2048, 2048, 2560, sA, sB);
        return;
    }
    id -= 640;
    float (*tile)[33] = (float(*)[33])sA;   // alias transpose tile into sA
    const float* in; short* out; int R, Cc, xt, yt;
    if (id < 4096)      { in = Wo; out = WoT; R = 2048; Cc = 2048; xt = id & 63; yt = id >> 6; }
    else if (id < 5120) { id -= 4096; in = Wk; out = WkT; R = 512; Cc = 2048; xt = id & 63; yt = id >> 6; }
    else                { id -= 5120; in = Wv; out = WvT; R = 512; Cc = 2048; xt = id & 63; yt = id >> 6; }
    const int c0 = xt * 32, r0 = yt * 32;
    const int t = threadIdx.x;
    const int tx = t & 31, ty = t >> 5;
#pragma unroll
    for (int i = 0; i < 32; i += 8)
        tile[ty + i][tx] = in[(size_t)(r0 + ty + i) * Cc + c0 + tx];
    __syncthreads();
#pragma unroll
    for (int i = 0; i < 32; i += 8)
        out[(size_t)(c0 + ty + i) * R + r0 + tx] = f2bf(tile[tx][ty + i]);
}

// ============================================================================
// 256x256 8-phase bf16 GEMM (T2+T3+T4+T5) — kv dispatch (exact 256-block fill).
// Row-pair bank swizzle (SQ_LDS_BANK_CONFLICT == 0). Counted vmcnt, never 0.
// ============================================================================
#define LBASE(buf, kh, ab) ((((((buf) << 1) | (kh)) << 1) | (ab)) * 8192)

#define STAGE(P, ld, tt, kh, buf, ab)                                   \
    do {                                                                \
        const int kb_ = (tt) * 64 + (kh) * 32;                          \
        const short* s_ = (P) + kb_;                                    \
        short* d_ = lds + LBASE(buf, kh, ab) + w * 512;                 \
        gload_lds16(s_, d_);                                            \
        gload_lds16(s_ + (size_t)128 * (ld), d_ + 4096);                \
    } while (0)

#define VM6 asm volatile("s_waitcnt vmcnt(6)" ::: "memory")

#define MFMA16(a, b, c) __builtin_amdgcn_mfma_f32_16x16x32_bf16(a, b, c, 0, 0, 0)

#define MM_ROW(mi, areg)                                                \
    acc[mi][0] = MFMA16(areg, bv0, acc[mi][0]);                         \
    acc[mi][1] = MFMA16(areg, bv1, acc[mi][1]);                         \
    acc[mi][2] = MFMA16(areg, bv2, acc[mi][2]);                         \
    acc[mi][3] = MFMA16(areg, bv3, acc[mi][3]);

#define HALFK(buf, kh, STG0, W0, STG1)                                  \
    {                                                                   \
        bf16x8 bv0, bv1, bv2, bv3;                                      \
        {                                                               \
            const short* Ab_ = lds + LBASE(buf, kh, 0) + (wm * 128) * 32 + foff; \
            const short* Bb_ = lds + LBASE(buf, kh, 1) + (wn * 64) * 32 + foff;  \
            bf16x8 a0_ = *(const bf16x8*)&Ab_[0];                       \
            bf16x8 a1_ = *(const bf16x8*)&Ab_[512];                     \
            bf16x8 a2_ = *(const bf16x8*)&Ab_[1024];                    \
            bf16x8 a3_ = *(const bf16x8*)&Ab_[1536];                    \
            bv0 = *(const bf16x8*)&Bb_[0];                              \
            bv1 = *(const bf16x8*)&Bb_[512];                            \
            bv2 = *(const bf16x8*)&Bb_[1024];                           \
            bv3 = *(const bf16x8*)&Bb_[1536];                           \
            STG0;                                                       \
            W0;                                                         \
            __builtin_amdgcn_s_barrier();                               \
            asm volatile("s_waitcnt lgkmcnt(0)" ::: "memory");          \
            __builtin_amdgcn_sched_barrier(0);                          \
            __builtin_amdgcn_s_setprio(1);                              \
            MM_ROW(0, a0_) MM_ROW(1, a1_) MM_ROW(2, a2_) MM_ROW(3, a3_) \
            __builtin_amdgcn_s_setprio(0);                              \
            __builtin_amdgcn_s_barrier();                               \
        }                                                               \
        {                                                               \
            const short* Ab_ = lds + LBASE(buf, kh, 0) + (wm * 128 + 64) * 32 + foff; \
            bf16x8 a0_ = *(const bf16x8*)&Ab_[0];                       \
            bf16x8 a1_ = *(const bf16x8*)&Ab_[512];                     \
            bf16x8 a2_ = *(const bf16x8*)&Ab_[1024];                    \
            bf16x8 a3_ = *(const bf16x8*)&Ab_[1536];                    \
            STG1;                                                       \
            __builtin_amdgcn_s_barrier();                               \
            asm volatile("s_waitcnt lgkmcnt(0)" ::: "memory");          \
            __builtin_amdgcn_sched_barrier(0);                          \
            __builtin_amdgcn_s_setprio(1);                              \
            MM_ROW(4, a0_) MM_ROW(5, a1_) MM_ROW(6, a2_) MM_ROW(7, a3_) \
            __builtin_amdgcn_s_setprio(0);                              \
            __builtin_amdgcn_s_barrier();                               \
        }                                                               \
    }

template <typename OutT>
__device__ __forceinline__ void gemm256_core(
    const short* __restrict__ A, const short* __restrict__ Bt, OutT* __restrict__ C,
    int m0, int n0, int K, int lda, int ldb, int ldc, short* lds) {
    const int t = threadIdx.x;
    const int w = t >> 6, l = t & 63;
    const int wm = w >> 2, wn = w & 3;
    const int l15 = l & 15, lc = l >> 4;

    // staging (row-pair swizzle, inverse perm on the global source)
    const int su = (l & 7) ^ ((l >> 3) & 7);
    const int srow = (w << 4) + ((l >> 3) << 1) + (su >> 2);
    const int scol = (su & 3) << 3;
    const short* Ag = A + (size_t)(m0 + srow) * lda + scol;
    const short* Bg = Bt + (size_t)(n0 + srow) * ldb + scol;

    // frag read (row-pair swizzle)
    const int i3 = ((((l15 & 1) << 2) | lc) ^ ((l15 >> 1) & 7));
    const int foff = (l15 >> 1) * 64 + i3 * 8;

    f32x4 acc[8][4] = {};

    const int ntm1 = (K >> 6) - 1;
    const int niter = K >> 7;   // 2 K-tiles per iteration

    STAGE(Ag, lda, 0, 0, 0, 0);
    STAGE(Bg, ldb, 0, 0, 0, 1);
    STAGE(Ag, lda, 0, 1, 0, 0);
    STAGE(Bg, ldb, 0, 1, 0, 1);
    STAGE(Ag, lda, 1, 0, 1, 0);
    STAGE(Bg, ldb, 1, 0, 1, 1);
    asm volatile("s_waitcnt vmcnt(8)" ::: "memory");
    __builtin_amdgcn_s_barrier();

#pragma unroll 1
    for (int it = 0; it < niter; ++it) {
        const int tt = it * 2;
        const int t1 = tt + 1;
        const int t2 = (tt + 2 > ntm1) ? ntm1 : tt + 2;
        const int t3 = (tt + 3 > ntm1) ? ntm1 : tt + 3;
        HALFK(0, 0, STAGE(Ag, lda, t1, 1, 1, 0), VM6, STAGE(Bg, ldb, t1, 1, 1, 1))
        HALFK(0, 1, STAGE(Ag, lda, t2, 0, 0, 0), VM6, STAGE(Bg, ldb, t2, 0, 0, 1))
        HALFK(1, 0, STAGE(Ag, lda, t2, 1, 0, 0), VM6, STAGE(Bg, ldb, t2, 1, 0, 1))
        HALFK(1, 1, STAGE(Ag, lda, t3, 0, 1, 0), VM6, STAGE(Bg, ldb, t3, 0, 1, 1))
    }

    asm volatile("s_waitcnt vmcnt(0)" ::: "memory");

    const int crow = m0 + wm * 128 + lc * 4;
    const int ccol = n0 + wn * 64 + l15;
#pragma unroll
    for (int mi = 0; mi < 8; ++mi)
#pragma unroll
        for (int ni = 0; ni < 4; ++ni) {
            OutT* cp = C + (size_t)(crow + mi * 16) * ldc + ccol + ni * 16;
#pragma unroll
            for (int rr = 0; rr < 4; ++rr)
                store_out(cp + (size_t)rr * ldc, acc[mi][ni][rr]);
        }
}

// fused kk + vT GEMMs (both K=512), 256 blocks -> exact full-chip fill
__global__ __launch_bounds__(512, 2)
void gemm256_kv(const short* __restrict__ kvl, const short* __restrict__ WkT,
                short* __restrict__ kk, const short* __restrict__ WvT,
                short* __restrict__ vT) {
    extern __shared__ short lds[];
    int id = blockIdx.x;
    if (id < 128) {
        gemm256_core<short>(kvl, WkT, kk, (id >> 3) * 256, (id & 7) * 256,
                            512, 2560, 512, 2048, lds);
    } else {
        id -= 128;
        gemm256_core<short>(WvT, kvl, vT, (id >> 4) * 256, (id & 15) * 256,
                            512, 512, 2560, 4096, lds);
    }
}

// ============================================================================
// ASYM pipelined bf16 GEMM: BM=256, BN=128 — out-projection (256 blocks, exact
// 1/CU fill). 8 waves as 4M x 2N, wave-tile 64x64, acc[4][4] f32x4.
// 4-slot ring (96 KiB LDS), stage p+3, vmcnt(6) (round-5 proven config; the
// 6-slot deepening was null -> staging-traffic-bound, not latency-bound).
// ROUND-7: 1D grid + XCD-chunked bijective swizzle (256 = 8*32): XCD k gets
// logical tiles [32k,32k+32) = 2 A-panels x 16 n -> A-panels L2-local (x16).
// ============================================================================
#define LB2(s) ((s) * 12288)   // 24 KiB slots: A at +0 (8192 sh), B at +8192

#define STG2(ps, pt)                                                    \
    do {                                                                \
        const int kb_ = (pt) * 32;                                      \
        gload_lds16(Ag + kb_, lds + LB2(ps) + w * 512);                 \
        gload_lds16(Ag + kb_ + (size_t)128 * lda, lds + LB2(ps) + 4096 + w * 512); \
        gload_lds16(Bg + kb_, lds + LB2(ps) + 8192 + w * 512);          \
    } while (0)

#define PH2(s, ps, pt)                                                  \
    {                                                                   \
        const short* Ab_ = lds + LB2(s) + wm * 2048 + foff;             \
        const short* Bb_ = lds + LB2(s) + 8192 + wn * 2048 + foff;      \
        bf16x8 a0_ = *(const bf16x8*)&Ab_[0];                           \
        bf16x8 a1_ = *(const bf16x8*)&Ab_[512];                         \
        bf16x8 a2_ = *(const bf16x8*)&Ab_[1024];                        \
        bf16x8 a3_ = *(const bf16x8*)&Ab_[1536];                        \
        bf16x8 b0_ = *(const bf16x8*)&Bb_[0];                           \
        bf16x8 b1_ = *(const bf16x8*)&Bb_[512];                         \
        bf16x8 b2_ = *(const bf16x8*)&Bb_[1024];                        \
        bf16x8 b3_ = *(const bf16x8*)&Bb_[1536];                        \
        STG2(ps, pt);                                                   \
        asm volatile("s_waitcnt vmcnt(6)" ::: "memory");                \
        __builtin_amdgcn_s_barrier();                                   \
        asm volatile("s_waitcnt lgkmcnt(0)" ::: "memory");              \
        __builtin_amdgcn_sched_barrier(0);                              \
        __builtin_amdgcn_s_setprio(1);                                  \
        acc[0][0]=MFMA16(a0_,b0_,acc[0][0]); acc[0][1]=MFMA16(a0_,b1_,acc[0][1]); \
        acc[0][2]=MFMA16(a0_,b2_,acc[0][2]); acc[0][3]=MFMA16(a0_,b3_,acc[0][3]); \
        acc[1][0]=MFMA16(a1_,b0_,acc[1][0]); acc[1][1]=MFMA16(a1_,b1_,acc[1][1]); \
        acc[1][2]=MFMA16(a1_,b2_,acc[1][2]); acc[1][3]=MFMA16(a1_,b3_,acc[1][3]); \
        acc[2][0]=MFMA16(a2_,b0_,acc[2][0]); acc[2][1]=MFMA16(a2_,b1_,acc[2][1]); \
        acc[2][2]=MFMA16(a2_,b2_,acc[2][2]); acc[2][3]=MFMA16(a2_,b3_,acc[2][3]); \
        acc[3][0]=MFMA16(a3_,b0_,acc[3][0]); acc[3][1]=MFMA16(a3_,b1_,acc[3][1]); \
        acc[3][2]=MFMA16(a3_,b2_,acc[3][2]); acc[3][3]=MFMA16(a3_,b3_,acc[3][3]); \
        __builtin_amdgcn_s_setprio(0);                                  \
        __builtin_amdgcn_s_barrier();                                   \
    }

__global__ __launch_bounds__(512, 1)
void gemm_out(const short* __restrict__ A, const short* __restrict__ Bt,
              float* __restrict__ C, int K, int lda, int ldb, int ldc) {
    extern __shared__ short lds[];
    // XCD-chunked bijective swizzle: 256 blocks = 8 XCDs x 32 tiles
    const int sw = ((int)blockIdx.x & 7) * 32 + ((int)blockIdx.x >> 3);
    const int m0 = (sw >> 4) * 256, n0 = (sw & 15) * 128;
    const int t = threadIdx.x;
    const int w = t >> 6, l = t & 63;
    const int wm = w >> 1, wn = w & 1;
    const int l15 = l & 15, lc = l >> 4;

    // staging source (row-pair inverse swizzle; identical formulas to gemm256)
    const int su = (l & 7) ^ ((l >> 3) & 7);
    const int srow = (w << 4) + ((l >> 3) << 1) + (su >> 2);
    const int scol = (su & 3) << 3;
    const short* Ag = A + (size_t)(m0 + srow) * lda + scol;
    const short* Bg = Bt + (size_t)(n0 + srow) * ldb + scol;

    // frag read offset (row-pair swizzle; rbase%16==0 for all frags)
    const int i3 = ((((l15 & 1) << 2) | lc) ^ ((l15 >> 1) & 7));
    const int foff = (l15 >> 1) * 64 + i3 * 8;

    f32x4 acc[4][4] = {};

    const int nkh1 = (K >> 5) - 1;   // last K-half index

    // prologue: stage K-halves 0,1,2 (9 gloads); ensure kh0 landed
    STG2(0, 0);
    STG2(1, 1);
    STG2(2, 2);
    asm volatile("s_waitcnt vmcnt(6)" ::: "memory");
    __builtin_amdgcn_s_barrier();

#pragma unroll 1
    for (int it = 0; it < (K >> 7); ++it) {
        const int h0 = it * 4;
        const int p3 = h0 + 3;   // never exceeds nkh1
        const int p4 = (h0 + 4 > nkh1) ? nkh1 : h0 + 4;   // tail: re-fetch last kh
        const int p5 = (h0 + 5 > nkh1) ? nkh1 : h0 + 5;   // into dead slots
        const int p6 = (h0 + 6 > nkh1) ? nkh1 : h0 + 6;
        PH2(0, 3, p3)
        PH2(1, 0, p4)
        PH2(2, 1, p5)
        PH2(3, 2, p6)
    }

    asm volatile("s_waitcnt vmcnt(0)" ::: "memory");  // drain tail garbage stages

    // epilogue: C/D 16x16 layout: col = l&15, row = (l>>4)*4 + reg
    const int crow = m0 + wm * 64 + lc * 4;
    const int ccol = n0 + wn * 64 + l15;
#pragma unroll
    for (int mi = 0; mi < 4; ++mi)
#pragma unroll
        for (int ni = 0; ni < 4; ++ni) {
            float* cp = C + (size_t)(crow + mi * 16) * ldc + ccol + ni * 16;
#pragma unroll
            for (int rr = 0; rr < 4; ++rr)
                store_out(cp + (size_t)rr * ldc, acc[mi][ni][rr]);
        }
}

// ---------- attention: sliding window 128 + sink 16, causal; full-MFMA ----------
#define A_S 2048
#define A_D 2048
#define A_M 4096
#define A_HD 128
__global__ __launch_bounds__(256)
void attn_win3(const short* __restrict__ Q, const short* __restrict__ K,
               const short* __restrict__ vT, short* __restrict__ O, int ldq) {
    const int qt = blockIdx.x, h = blockIdx.y, b = blockIdx.z;
    const int Qs = qt * 64;
    const int t = threadIdx.x, w = t >> 6, l = t & 63;
    const int qs = Qs + w * 16;
    const int lg = l >> 4, ln = l & 15;
    const float SCALE = 0.088388347648318447f;  // 1/sqrt(128)

    __shared__ __align__(16) short sK[2][512 * 8];
    __shared__ __align__(16) short sV[2][512 * 8];
    __shared__ __align__(16) short sP[4][16][40];   // bf16 P, stride 40

    const size_t bS = (size_t)b * A_S;
    const short* qrow = Q + (bS + qs + ln) * ldq + h * A_HD;
    bf16x8 qf[4];
#pragma unroll
    for (int ks = 0; ks < 4; ++ks)
        qf[ks] = *(const bf16x8*)(qrow + ks * 32 + lg * 8);

    f32x4 o[8] = {};
    float lsum[4] = {0.f, 0.f, 0.f, 0.f};

    int C_lo = (Qs - 127) >> 5; if (C_lo < 0) C_lo = 0;
    const int C_hi = (Qs + 63) >> 5;
    const bool sink = C_lo > 0;
    const int total = (C_hi - C_lo + 1) + (sink ? 1 : 0);

    const int key0 = t >> 4, dseg0s = (t & 15) ^ (key0 & 7);
    const int d0 = t >> 2, ksg0 = (t & 3) ^ ((d0 >> 1) & 3);
    const int key1 = (256 + t) >> 4, dseg1s = (t & 15) ^ (key1 & 7);
    const int d1 = (256 + t) >> 2, ksg1 = (t & 3) ^ ((d1 >> 1) & 3);
    const short* Kb = K + bS * A_D + h * A_HD;
    const short* Vb = vT + (size_t)h * A_HD * A_M + b * A_S;

#define ASTAGE(kb, buf)                                                         \
    do {                                                                        \
        gload_lds16(Kb + (size_t)((kb) + key0) * A_D + dseg0s * 8,              \
                    &sK[buf][(size_t)(w * 64) * 8]);                            \
        gload_lds16(Vb + (size_t)d0 * A_M + (kb) + ksg0 * 8,                    \
                    &sV[buf][(size_t)(w * 64) * 8]);                            \
        gload_lds16(Kb + (size_t)((kb) + key1) * A_D + dseg1s * 8,              \
                    &sK[buf][(size_t)(256 + w * 64) * 8]);                      \
        gload_lds16(Vb + (size_t)d1 * A_M + (kb) + ksg1 * 8,                    \
                    &sV[buf][(size_t)(256 + w * 64) * 8]);                      \
    } while (0)

#define CHUNK_KB(ci) ((((sink) && (ci) == 0) ? 0 : (C_lo + (ci) - (sink ? 1 : 0))) * 32)

    ASTAGE(CHUNK_KB(0), 0);
    __syncthreads();

    for (int ci = 0; ci < total; ++ci) {
        if (ci + 1 < total) {
            const int nkb = CHUNK_KB(ci + 1);
            ASTAGE(nkb, (ci + 1) & 1);
        }
        const int kb = CHUNK_KB(ci);
        const int buf = ci & 1;
        const bool any = (kb < 16) || ((kb + 31 >= qs - 127) && (kb <= qs + 15));
        if (any) {
            f32x4 s0 = {0.f, 0.f, 0.f, 0.f}, s1 = {0.f, 0.f, 0.f, 0.f};
#pragma unroll
            for (int ks = 0; ks < 4; ++ks) {
                const int dsg = ks * 4 + lg;
                bf16x8 k0 = *(const bf16x8*)&sK[buf][(ln * 16 + (dsg ^ (ln & 7))) * 8];
                bf16x8 k1 = *(const bf16x8*)&sK[buf][((16 + ln) * 16 + (dsg ^ (ln & 7))) * 8];
                s0 = __builtin_amdgcn_mfma_f32_16x16x32_bf16(qf[ks], k0, s0, 0, 0, 0);
                s1 = __builtin_amdgcn_mfma_f32_16x16x32_bf16(qf[ks], k1, s1, 0, 0, 0);
            }
            const int k0i = kb + ln, k1i = kb + 16 + ln;
#pragma unroll
            for (int r = 0; r < 4; ++r) {
                const int qi = qs + lg * 4 + r;
                const bool m0 = (k0i <= qi) && ((qi - k0i < 128) || (k0i < 16));
                const bool m1 = (k1i <= qi) && ((qi - k1i < 128) || (k1i < 16));
                const float p0 = m0 ? __expf(s0[r] * SCALE) : 0.f;
                const float p1 = m1 ? __expf(s1[r] * SCALE) : 0.f;
                lsum[r] += p0 + p1;
                sP[w][lg * 4 + r][ln] = f2bf(p0);
                sP[w][lg * 4 + r][16 + ln] = f2bf(p1);
            }
            bf16x8 pf = *(const bf16x8*)&sP[w][ln][lg * 8];
#pragma unroll
            for (int dgi = 0; dgi < 8; ++dgi) {
                const int d = dgi * 16 + ln;
                bf16x8 vf = *(const bf16x8*)&sV[buf][(d * 4 + (lg ^ ((ln >> 1) & 3))) * 8];
                o[dgi] = __builtin_amdgcn_mfma_f32_16x16x32_bf16(pf, vf, o[dgi], 0, 0, 0);
            }
        }
        __syncthreads();
    }
#undef ASTAGE
#undef CHUNK_KB

#pragma unroll
    for (int r = 0; r < 4; ++r) {
        float s = lsum[r];
        s += __shfl_xor(s, 1); s += __shfl_xor(s, 2);
        s += __shfl_xor(s, 4); s += __shfl_xor(s, 8);
        const float inv = 1.0f / s;
        short* orow = O + (bS + qs + lg * 4 + r) * A_D + h * A_HD + ln;
#pragma unroll
        for (int dgi = 0; dgi < 8; ++dgi)
            orow[dgi * 16] = f2bf(o[dgi][r] * inv);
    }
}

// ---------- host ----------
extern "C" void kernel_launch(void* const* d_in, const int* in_sizes, int n_in,
                              void* d_out, int out_size, void* d_ws, size_t ws_size,
                              hipStream_t stream) {
    (void)in_sizes; (void)n_in; (void)out_size; (void)ws_size;
    const float* x   = (const float*)d_in[0];
    const float* Wq  = (const float*)d_in[1];
    const float* Wkv = (const float*)d_in[2];
    const float* Wk  = (const float*)d_in[3];
    const float* Wv  = (const float*)d_in[4];
    const float* Wo  = (const float*)d_in[5];
    float* out = (float*)d_out;

    const int B = 2, S = 2048, D = 2048, L = 512, H = 16;
    const int M = B * S;       // 4096
    const int NQ = D + L;      // 2560 (fused q|kvl)

    short* p = (short*)d_ws;
    short* xb    = p; p += (size_t)M * D;
    short* WqkvT = p; p += (size_t)NQ * D;
    short* WkT   = p; p += (size_t)D * L;
    short* WvT   = p; p += (size_t)D * L;
    short* WoT   = p; p += (size_t)D * D;
    short* qkv   = p; p += (size_t)M * NQ;
    short* kk    = p; p += (size_t)M * D;
    short* vT    = p; p += (size_t)D * M;
    short* ao    = p; p += (size_t)M * D;

    // dynamic-LDS opt-ins (once; host-side, graph-capture safe)
    static bool attr_done = false;
    if (!attr_done) {
        hipFuncSetAttribute((const void*)&gemm256_kv,
                            hipFuncAttributeMaxDynamicSharedMemorySize, 131072);
        hipFuncSetAttribute((const void*)&gemm_out,
                            hipFuncAttributeMaxDynamicSharedMemorySize, 98304);
        attr_done = true;
    }

    // prep: x cvt + Wq/Wkv transposes (qkv inputs only)
    prep_all<<<13312, 256, 0, stream>>>(x, xb, Wq, Wkv, WqkvT);
    // qkv GEMM (640 blocks, XCD-swizzled) + Wo/Wk/Wv transposes (6144 tail blocks)
    gemm32qkv<<<6784, 256, 0, stream>>>(xb, WqkvT, qkv, Wo, Wk, Wv,
                                        WoT, WkT, WvT);
    // fused kk + vT GEMMs (256 blocks, exact fill, 8-phase)
    gemm256_kv<<<256, 512, 131072, stream>>>(qkv + D, WkT, kk, WvT, vT);

    attn_win3<<<dim3(S / 64, H, B), 256, 0, stream>>>(qkv, kk, vT, ao, NQ);

    // out projection: 256 blocks 1D, XCD-swizzled, BM256xBN128 4-slot pipeline
    gemm_out<<<256, 512, 98304, stream>>>(ao, WoT, out, D, D, D, D);
}

// Round 8
// 253.515 us; speedup vs baseline: 1.0419x; 1.0419x over previous
//
#include <hip/hip_runtime.h>

// ---------- types ----------
typedef float f32x4 __attribute__((ext_vector_type(4)));
typedef __bf16 bf16x8 __attribute__((ext_vector_type(8)));

// ---------- bf16 helpers (RNE) ----------
__device__ __forceinline__ short f2bf(float f) {
    union { float f; unsigned u; } x; x.f = f;
    unsigned r = x.u + 0x7fffu + ((x.u >> 16) & 1u);
    return (short)(r >> 16);
}

__device__ __forceinline__ void store_out(float* p, float v) { *p = v; }
__device__ __forceinline__ void store_out(short* p, float v) { *p = f2bf(v); }

// async global->LDS; lds dest = wave-uniform base (HW adds lane*size)
__device__ __forceinline__ void gload_lds16(const short* g, short* l) {
    __builtin_amdgcn_global_load_lds(
        (__attribute__((address_space(1))) void*)(void*)g,
        (__attribute__((address_space(3))) void*)l, 16, 0, 0);
}
__device__ __forceinline__ void gload_lds4(const short* g, short* l) {
    __builtin_amdgcn_global_load_lds(
        (__attribute__((address_space(1))) void*)(void*)g,
        (__attribute__((address_space(3))) void*)l, 4, 0, 0);
}

// ---------- fused prep: x->bf16 cvt + ALL weight transposes, one dispatch ----
__global__ void prep_all(const float* __restrict__ x, short* __restrict__ xb,
                         const float* __restrict__ Wq, const float* __restrict__ Wo,
                         const float* __restrict__ Wk, const float* __restrict__ Wv,
                         const float* __restrict__ Wkv,
                         short* __restrict__ WqkvT, short* __restrict__ WoT,
                         short* __restrict__ WkT, short* __restrict__ WvT) {
    __shared__ float tile[32][33];
    int id = blockIdx.x;
    const int t = threadIdx.x;
    if (id < 8192) {
        const int i = id * 256 + t;
        float4 v = ((const float4*)x)[i];
        ((short4*)xb)[i] = make_short4(f2bf(v.x), f2bf(v.y), f2bf(v.z), f2bf(v.w));
        return;
    }
    id -= 8192;
    const float* in; short* out; int R, C, xt, yt;
    if (id < 4096)       { in = Wq;  out = WqkvT; R = 2048; C = 2048; xt = id & 63; yt = id >> 6; }
    else if (id < 8192)  { id -= 4096; in = Wo;  out = WoT;  R = 2048; C = 2048; xt = id & 63; yt = id >> 6; }
    else if (id < 9216)  { id -= 8192; in = Wk;  out = WkT;  R = 512;  C = 2048; xt = id & 63; yt = id >> 6; }
    else if (id < 10240) { id -= 9216; in = Wv;  out = WvT;  R = 512;  C = 2048; xt = id & 63; yt = id >> 6; }
    else                 { id -= 10240; in = Wkv; out = WqkvT + (size_t)2048 * 2048;
                           R = 2048; C = 512; xt = id & 15; yt = id >> 4; }
    const int c0 = xt * 32, r0 = yt * 32;
    const int tx = t & 31, ty = t >> 5;
#pragma unroll
    for (int i = 0; i < 32; i += 8)
        tile[ty + i][tx] = in[(size_t)(r0 + ty + i) * C + c0 + tx];
    __syncthreads();
#pragma unroll
    for (int i = 0; i < 32; i += 8)
        out[(size_t)(c0 + ty + i) * R + r0 + tx] = f2bf(tile[tx][ty + i]);
}

#define MFMA16(a, b, c) __builtin_amdgcn_mfma_f32_16x16x32_bf16(a, b, c, 0, 0, 0)

// ============================================================================
// 256x256 8-phase bf16 GEMM — kv dispatch (exact 256-block fill, K=512).
// Row-pair bank swizzle (SQ_LDS_BANK_CONFLICT == 0). Counted vmcnt, never 0.
// ============================================================================
#define LBASE(buf, kh, ab) ((((((buf) << 1) | (kh)) << 1) | (ab)) * 8192)

#define STAGE(P, ld, tt, kh, buf, ab)                                   \
    do {                                                                \
        const int kb_ = (tt) * 64 + (kh) * 32;                          \
        const short* s_ = (P) + kb_;                                    \
        short* d_ = lds + LBASE(buf, kh, ab) + w * 512;                 \
        gload_lds16(s_, d_);                                            \
        gload_lds16(s_ + (size_t)128 * (ld), d_ + 4096);                \
    } while (0)

#define VM6 asm volatile("s_waitcnt vmcnt(6)" ::: "memory")

#define MM_ROW(mi, areg)                                                \
    acc[mi][0] = MFMA16(areg, bv0, acc[mi][0]);                         \
    acc[mi][1] = MFMA16(areg, bv1, acc[mi][1]);                         \
    acc[mi][2] = MFMA16(areg, bv2, acc[mi][2]);                         \
    acc[mi][3] = MFMA16(areg, bv3, acc[mi][3]);

#define HALFK(buf, kh, STG0, W0, STG1)                                  \
    {                                                                   \
        bf16x8 bv0, bv1, bv2, bv3;                                      \
        {                                                               \
            const short* Ab_ = lds + LBASE(buf, kh, 0) + (wm * 128) * 32 + foff; \
            const short* Bb_ = lds + LBASE(buf, kh, 1) + (wn * 64) * 32 + foff;  \
            bf16x8 a0_ = *(const bf16x8*)&Ab_[0];                       \
            bf16x8 a1_ = *(const bf16x8*)&Ab_[512];                     \
            bf16x8 a2_ = *(const bf16x8*)&Ab_[1024];                    \
            bf16x8 a3_ = *(const bf16x8*)&Ab_[1536];                    \
            bv0 = *(const bf16x8*)&Bb_[0];                              \
            bv1 = *(const bf16x8*)&Bb_[512];                            \
            bv2 = *(const bf16x8*)&Bb_[1024];                           \
            bv3 = *(const bf16x8*)&Bb_[1536];                           \
            STG0;                                                       \
            W0;                                                         \
            __builtin_amdgcn_s_barrier();                               \
            asm volatile("s_waitcnt lgkmcnt(0)" ::: "memory");          \
            __builtin_amdgcn_sched_barrier(0);                          \
            __builtin_amdgcn_s_setprio(1);                              \
            MM_ROW(0, a0_) MM_ROW(1, a1_) MM_ROW(2, a2_) MM_ROW(3, a3_) \
            __builtin_amdgcn_s_setprio(0);                              \
            __builtin_amdgcn_s_barrier();                               \
        }                                                               \
        {                                                               \
            const short* Ab_ = lds + LBASE(buf, kh, 0) + (wm * 128 + 64) * 32 + foff; \
            bf16x8 a0_ = *(const bf16x8*)&Ab_[0];                       \
            bf16x8 a1_ = *(const bf16x8*)&Ab_[512];                     \
            bf16x8 a2_ = *(const bf16x8*)&Ab_[1024];                    \
            bf16x8 a3_ = *(const bf16x8*)&Ab_[1536];                    \
            STG1;                                                       \
            __builtin_amdgcn_s_barrier();                               \
            asm volatile("s_waitcnt lgkmcnt(0)" ::: "memory");          \
            __builtin_amdgcn_sched_barrier(0);                          \
            __builtin_amdgcn_s_setprio(1);                              \
            MM_ROW(4, a0_) MM_ROW(5, a1_) MM_ROW(6, a2_) MM_ROW(7, a3_) \
            __builtin_amdgcn_s_setprio(0);                              \
            __builtin_amdgcn_s_barrier();                               \
        }                                                               \
    }

template <typename OutT>
__device__ __forceinline__ void gemm256_core(
    const short* __restrict__ A, const short* __restrict__ Bt, OutT* __restrict__ C,
    int m0, int n0, int K, int lda, int ldb, int ldc, short* lds) {
    const int t = threadIdx.x;
    const int w = t >> 6, l = t & 63;
    const int wm = w >> 2, wn = w & 3;
    const int l15 = l & 15, lc = l >> 4;

    const int su = (l & 7) ^ ((l >> 3) & 7);
    const int srow = (w << 4) + ((l >> 3) << 1) + (su >> 2);
    const int scol = (su & 3) << 3;
    const short* Ag = A + (size_t)(m0 + srow) * lda + scol;
    const short* Bg = Bt + (size_t)(n0 + srow) * ldb + scol;

    const int i3 = ((((l15 & 1) << 2) | lc) ^ ((l15 >> 1) & 7));
    const int foff = (l15 >> 1) * 64 + i3 * 8;

    f32x4 acc[8][4] = {};

    const int ntm1 = (K >> 6) - 1;
    const int niter = K >> 7;

    STAGE(Ag, lda, 0, 0, 0, 0);
    STAGE(Bg, ldb, 0, 0, 0, 1);
    STAGE(Ag, lda, 0, 1, 0, 0);
    STAGE(Bg, ldb, 0, 1, 0, 1);
    STAGE(Ag, lda, 1, 0, 1, 0);
    STAGE(Bg, ldb, 1, 0, 1, 1);
    asm volatile("s_waitcnt vmcnt(8)" ::: "memory");
    __builtin_amdgcn_s_barrier();

#pragma unroll 1
    for (int it = 0; it < niter; ++it) {
        const int tt = it * 2;
        const int t1 = tt + 1;
        const int t2 = (tt + 2 > ntm1) ? ntm1 : tt + 2;
        const int t3 = (tt + 3 > ntm1) ? ntm1 : tt + 3;
        HALFK(0, 0, STAGE(Ag, lda, t1, 1, 1, 0), VM6, STAGE(Bg, ldb, t1, 1, 1, 1))
        HALFK(0, 1, STAGE(Ag, lda, t2, 0, 0, 0), VM6, STAGE(Bg, ldb, t2, 0, 0, 1))
        HALFK(1, 0, STAGE(Ag, lda, t2, 1, 0, 0), VM6, STAGE(Bg, ldb, t2, 1, 0, 1))
        HALFK(1, 1, STAGE(Ag, lda, t3, 0, 1, 0), VM6, STAGE(Bg, ldb, t3, 0, 1, 1))
    }

    asm volatile("s_waitcnt vmcnt(0)" ::: "memory");

    const int crow = m0 + wm * 128 + lc * 4;
    const int ccol = n0 + wn * 64 + l15;
#pragma unroll
    for (int mi = 0; mi < 8; ++mi)
#pragma unroll
        for (int ni = 0; ni < 4; ++ni) {
            OutT* cp = C + (size_t)(crow + mi * 16) * ldc + ccol + ni * 16;
#pragma unroll
            for (int rr = 0; rr < 4; ++rr)
                store_out(cp + (size_t)rr * ldc, acc[mi][ni][rr]);
        }
}

// fused kk + vT GEMMs (both K=512), 256 blocks -> exact full-chip fill
__global__ __launch_bounds__(512, 2)
void gemm256_kv(const short* __restrict__ kvl, const short* __restrict__ WkT,
                short* __restrict__ kk, const short* __restrict__ WvT,
                short* __restrict__ vT) {
    extern __shared__ short lds[];
    int id = blockIdx.x;
    if (id < 128) {
        gemm256_core<short>(kvl, WkT, kk, (id >> 3) * 256, (id & 7) * 256,
                            512, 2560, 512, 2048, lds);
    } else {
        id -= 128;
        gemm256_core<short>(WvT, kvl, vT, (id >> 4) * 256, (id & 15) * 256,
                            512, 512, 2560, 4096, lds);
    }
}

// ============================================================================
// qkv GEMM: BM=256 x BN=160 asym pipelined — grid 16x16 = EXACTLY 256 blocks
// (1/CU; breaks the 2560=20x128 quantization lockout). 8 waves as 4M x 2N,
// per-wave 64x80, acc[4][5], 20 MFMA/phase. One phase per K-half (32k).
// LDS: 4-slot ring x (A 16 KB + B 10 KB) = 104 KiB. Staging per K-half:
// 2x16B calls (A rows 0-127 / 128-255) + 1x16B call (B rows 0-127) +
// 1x FULL-512-LANE 4B call (B rows 128-159 = 2048 B exactly) -> uniform
// 4 loads/wave/half, vmcnt(8) = oldest of 3 in-flight halves landed.
// Same row-pair swizzle (all frag row-bases === 0 mod 16); 4B path uses the
// per-lane inverse swizzle (verified by enumeration). XCD swizzle 256 = 8x32.
// ============================================================================
#define LQ(s) ((s) * 13312)   // slot stride shorts: A 8192 + B(16B) 4096 + B(4B) 1024

#define QSTG(ps, pt)                                                    \
    do {                                                                \
        const int kb_ = (pt) * 32;                                      \
        gload_lds16(Ag + kb_, lds + LQ(ps) + w * 512);                  \
        gload_lds16(Ag + kb_ + (size_t)128 * lda, lds + LQ(ps) + 4096 + w * 512); \
        gload_lds16(Bg + kb_, lds + LQ(ps) + 8192 + w * 512);           \
        gload_lds4(B4 + kb_, lds + LQ(ps) + 12288 + w * 128);           \
    } while (0)

#define QPH(s, ps, pt)                                                  \
    {                                                                   \
        const short* Ab_ = lds + LQ(s) + wm * 2048 + foff;              \
        const short* Bb_ = lds + LQ(s) + 8192 + wn * 2560 + foff;       \
        bf16x8 a0_ = *(const bf16x8*)&Ab_[0];                           \
        bf16x8 a1_ = *(const bf16x8*)&Ab_[512];                         \
        bf16x8 a2_ = *(const bf16x8*)&Ab_[1024];                        \
        bf16x8 a3_ = *(const bf16x8*)&Ab_[1536];                        \
        bf16x8 b0_ = *(const bf16x8*)&Bb_[0];                           \
        bf16x8 b1_ = *(const bf16x8*)&Bb_[512];                         \
        bf16x8 b2_ = *(const bf16x8*)&Bb_[1024];                        \
        bf16x8 b3_ = *(const bf16x8*)&Bb_[1536];                        \
        bf16x8 b4_ = *(const bf16x8*)&Bb_[2048];                        \
        QSTG(ps, pt);                                                   \
        asm volatile("s_waitcnt vmcnt(8)" ::: "memory");                \
        __builtin_amdgcn_s_barrier();                                   \
        asm volatile("s_waitcnt lgkmcnt(0)" ::: "memory");              \
        __builtin_amdgcn_sched_barrier(0);                              \
        __builtin_amdgcn_s_setprio(1);                                  \
        acc[0][0]=MFMA16(a0_,b0_,acc[0][0]); acc[0][1]=MFMA16(a0_,b1_,acc[0][1]); \
        acc[0][2]=MFMA16(a0_,b2_,acc[0][2]); acc[0][3]=MFMA16(a0_,b3_,acc[0][3]); \
        acc[0][4]=MFMA16(a0_,b4_,acc[0][4]);                            \
        acc[1][0]=MFMA16(a1_,b0_,acc[1][0]); acc[1][1]=MFMA16(a1_,b1_,acc[1][1]); \
        acc[1][2]=MFMA16(a1_,b2_,acc[1][2]); acc[1][3]=MFMA16(a1_,b3_,acc[1][3]); \
        acc[1][4]=MFMA16(a1_,b4_,acc[1][4]);                            \
        acc[2][0]=MFMA16(a2_,b0_,acc[2][0]); acc[2][1]=MFMA16(a2_,b1_,acc[2][1]); \
        acc[2][2]=MFMA16(a2_,b2_,acc[2][2]); acc[2][3]=MFMA16(a2_,b3_,acc[2][3]); \
        acc[2][4]=MFMA16(a2_,b4_,acc[2][4]);                            \
        acc[3][0]=MFMA16(a3_,b0_,acc[3][0]); acc[3][1]=MFMA16(a3_,b1_,acc[3][1]); \
        acc[3][2]=MFMA16(a3_,b2_,acc[3][2]); acc[3][3]=MFMA16(a3_,b3_,acc[3][3]); \
        acc[3][4]=MFMA16(a3_,b4_,acc[3][4]);                            \
        __builtin_amdgcn_s_setprio(0);                                  \
        __builtin_amdgcn_s_barrier();                                   \
    }

__global__ __launch_bounds__(512, 1)
void gemm_qkv160(const short* __restrict__ A, const short* __restrict__ Bt,
                 short* __restrict__ C, int K, int lda, int ldb, int ldc) {
    extern __shared__ short lds[];
    // XCD-chunked bijective swizzle: 256 blocks = 8 XCDs x 32 tiles (2 A-panels x 16 n)
    const int sw = ((int)blockIdx.x & 7) * 32 + ((int)blockIdx.x >> 3);
    const int m0 = (sw >> 4) * 256, n0 = (sw & 15) * 160;
    const int t = threadIdx.x;
    const int w = t >> 6, l = t & 63;
    const int wm = w >> 1, wn = w & 1;
    const int l15 = l & 15, lc = l >> 4;

    // 16B staging source (row-pair inverse swizzle, rows 0-127 of each panel)
    const int su = (l & 7) ^ ((l >> 3) & 7);
    const int srow = (w << 4) + ((l >> 3) << 1) + (su >> 2);
    const int scol = (su & 3) << 3;
    const short* Ag = A + (size_t)(m0 + srow) * lda + scol;
    const short* Bg = Bt + (size_t)(n0 + srow) * ldb + scol;
    // 4B staging source for B rows 128-159 (2048 B, all 512 lanes):
    // lane t -> region byte 8192+4t -> slot16 = 512+(t>>2), rp = 64+(t>>5),
    // i3 = (t>>2)&7, u = i3^(rp&7)=(t>>2&7)^(t>>5&7), row = 2*rp+(u>>2),
    // k-chunk = u&3, in-chunk shorts = (t&3)*2.
    const int u4 = ((t >> 2) & 7) ^ ((t >> 5) & 7);
    const int b4row = 128 + ((t >> 5) << 1) + (u4 >> 2);
    const int b4off = ((u4 & 3) << 3) + ((t & 3) << 1);
    const short* B4 = Bt + (size_t)(n0 + b4row) * ldb + b4off;

    // frag read offset (row-pair swizzle; all frag row-bases % 16 == 0)
    const int i3 = ((((l15 & 1) << 2) | lc) ^ ((l15 >> 1) & 7));
    const int foff = (l15 >> 1) * 64 + i3 * 8;

    f32x4 acc[4][5] = {};
    const int last = (K >> 5) - 1;   // 63 for K=2048

    // prologue: halves 0,1,2 in flight (12 calls); vmcnt(8) -> half 0 landed
    QSTG(0, 0); QSTG(1, 1); QSTG(2, 2);
    asm volatile("s_waitcnt vmcnt(8)" ::: "memory");
    __builtin_amdgcn_s_barrier();

#pragma unroll 1
    for (int it = 0; it < (K >> 7); ++it) {
        const int h0 = it * 4;
        const int q3 = h0 + 3;                            // never exceeds last
        const int q4 = (h0 + 4 > last) ? last : h0 + 4;   // tail: dup-last into
        const int q5 = (h0 + 5 > last) ? last : h0 + 5;   // dead slots, drained
        const int q6 = (h0 + 6 > last) ? last : h0 + 6;   // by final vmcnt(0)
        QPH(0, 3, q3)
        QPH(1, 0, q4)
        QPH(2, 1, q5)
        QPH(3, 2, q6)
    }
    asm volatile("s_waitcnt vmcnt(0)" ::: "memory");

    // epilogue: C/D 16x16 layout: col = l&15, row = (l>>4)*4 + reg
    const int crow = m0 + wm * 64 + lc * 4;
    const int ccol = n0 + wn * 80 + l15;
#pragma unroll
    for (int mi = 0; mi < 4; ++mi)
#pragma unroll
        for (int ni = 0; ni < 5; ++ni) {
            short* cp = C + (size_t)(crow + mi * 16) * ldc + ccol + ni * 16;
#pragma unroll
            for (int rr = 0; rr < 4; ++rr)
                store_out(cp + (size_t)rr * ldc, acc[mi][ni][rr]);
        }
}

// ============================================================================
// ASYM pipelined bf16 GEMM: BM=256, BN=128 — out-projection (256 blocks, 1/CU).
// 4-slot ring (96 KiB), stage p+3, vmcnt(6). XCD-chunked swizzle (8x32).
// ============================================================================
#define LB2(s) ((s) * 12288)

#define STG2(ps, pt)                                                    \
    do {                                                                \
        const int kb_ = (pt) * 32;                                      \
        gload_lds16(Ag + kb_, lds + LB2(ps) + w * 512);                 \
        gload_lds16(Ag + kb_ + (size_t)128 * lda, lds + LB2(ps) + 4096 + w * 512); \
        gload_lds16(Bg + kb_, lds + LB2(ps) + 8192 + w * 512);          \
    } while (0)

#define PH2(s, ps, pt)                                                  \
    {                                                                   \
        const short* Ab_ = lds + LB2(s) + wm * 2048 + foff;             \
        const short* Bb_ = lds + LB2(s) + 8192 + wn * 2048 + foff;      \
        bf16x8 a0_ = *(const bf16x8*)&Ab_[0];                           \
        bf16x8 a1_ = *(const bf16x8*)&Ab_[512];                         \
        bf16x8 a2_ = *(const bf16x8*)&Ab_[1024];                        \
        bf16x8 a3_ = *(const bf16x8*)&Ab_[1536];                        \
        bf16x8 b0_ = *(const bf16x8*)&Bb_[0];                           \
        bf16x8 b1_ = *(const bf16x8*)&Bb_[512];                         \
        bf16x8 b2_ = *(const bf16x8*)&Bb_[1024];                        \
        bf16x8 b3_ = *(const bf16x8*)&Bb_[1536];                        \
        STG2(ps, pt);                                                   \
        asm volatile("s_waitcnt vmcnt(6)" ::: "memory");                \
        __builtin_amdgcn_s_barrier();                                   \
        asm volatile("s_waitcnt lgkmcnt(0)" ::: "memory");              \
        __builtin_amdgcn_sched_barrier(0);                              \
        __builtin_amdgcn_s_setprio(1);                                  \
        acc[0][0]=MFMA16(a0_,b0_,acc[0][0]); acc[0][1]=MFMA16(a0_,b1_,acc[0][1]); \
        acc[0][2]=MFMA16(a0_,b2_,acc[0][2]); acc[0][3]=MFMA16(a0_,b3_,acc[0][3]); \
        acc[1][0]=MFMA16(a1_,b0_,acc[1][0]); acc[1][1]=MFMA16(a1_,b1_,acc[1][1]); \
        acc[1][2]=MFMA16(a1_,b2_,acc[1][2]); acc[1][3]=MFMA16(a1_,b3_,acc[1][3]); \
        acc[2][0]=MFMA16(a2_,b0_,acc[2][0]); acc[2][1]=MFMA16(a2_,b1_,acc[2][1]); \
        acc[2][2]=MFMA16(a2_,b2_,acc[2][2]); acc[2][3]=MFMA16(a2_,b3_,acc[2][3]); \
        acc[3][0]=MFMA16(a3_,b0_,acc[3][0]); acc[3][1]=MFMA16(a3_,b1_,acc[3][1]); \
        acc[3][2]=MFMA16(a3_,b2_,acc[3][2]); acc[3][3]=MFMA16(a3_,b3_,acc[3][3]); \
        __builtin_amdgcn_s_setprio(0);                                  \
        __builtin_amdgcn_s_barrier();                                   \
    }

__global__ __launch_bounds__(512, 1)
void gemm_out(const short* __restrict__ A, const short* __restrict__ Bt,
              float* __restrict__ C, int K, int lda, int ldb, int ldc) {
    extern __shared__ short lds[];
    const int sw = ((int)blockIdx.x & 7) * 32 + ((int)blockIdx.x >> 3);
    const int m0 = (sw >> 4) * 256, n0 = (sw & 15) * 128;
    const int t = threadIdx.x;
    const int w = t >> 6, l = t & 63;
    const int wm = w >> 1, wn = w & 1;
    const int l15 = l & 15, lc = l >> 4;

    const int su = (l & 7) ^ ((l >> 3) & 7);
    const int srow = (w << 4) + ((l >> 3) << 1) + (su >> 2);
    const int scol = (su & 3) << 3;
    const short* Ag = A + (size_t)(m0 + srow) * lda + scol;
    const short* Bg = Bt + (size_t)(n0 + srow) * ldb + scol;

    const int i3 = ((((l15 & 1) << 2) | lc) ^ ((l15 >> 1) & 7));
    const int foff = (l15 >> 1) * 64 + i3 * 8;

    f32x4 acc[4][4] = {};

    const int nkh1 = (K >> 5) - 1;

    STG2(0, 0);
    STG2(1, 1);
    STG2(2, 2);
    asm volatile("s_waitcnt vmcnt(6)" ::: "memory");
    __builtin_amdgcn_s_barrier();

#pragma unroll 1
    for (int it = 0; it < (K >> 7); ++it) {
        const int h0 = it * 4;
        const int p3 = h0 + 3;
        const int p4 = (h0 + 4 > nkh1) ? nkh1 : h0 + 4;
        const int p5 = (h0 + 5 > nkh1) ? nkh1 : h0 + 5;
        const int p6 = (h0 + 6 > nkh1) ? nkh1 : h0 + 6;
        PH2(0, 3, p3)
        PH2(1, 0, p4)
        PH2(2, 1, p5)
        PH2(3, 2, p6)
    }

    asm volatile("s_waitcnt vmcnt(0)" ::: "memory");

    const int crow = m0 + wm * 64 + lc * 4;
    const int ccol = n0 + wn * 64 + l15;
#pragma unroll
    for (int mi = 0; mi < 4; ++mi)
#pragma unroll
        for (int ni = 0; ni < 4; ++ni) {
            float* cp = C + (size_t)(crow + mi * 16) * ldc + ccol + ni * 16;
#pragma unroll
            for (int rr = 0; rr < 4; ++rr)
                store_out(cp + (size_t)rr * ldc, acc[mi][ni][rr]);
        }
}

// ---------- attention: sliding window 128 + sink 16, causal; full-MFMA ----------
#define A_S 2048
#define A_D 2048
#define A_M 4096
#define A_HD 128
__global__ __launch_bounds__(256)
void attn_win3(const short* __restrict__ Q, const short* __restrict__ K,
               const short* __restrict__ vT, short* __restrict__ O, int ldq) {
    const int qt = blockIdx.x, h = blockIdx.y, b = blockIdx.z;
    const int Qs = qt * 64;
    const int t = threadIdx.x, w = t >> 6, l = t & 63;
    const int qs = Qs + w * 16;
    const int lg = l >> 4, ln = l & 15;
    const float SCALE = 0.088388347648318447f;  // 1/sqrt(128)

    __shared__ __align__(16) short sK[2][512 * 8];
    __shared__ __align__(16) short sV[2][512 * 8];
    __shared__ __align__(16) short sP[4][16][40];   // bf16 P, stride 40

    const size_t bS = (size_t)b * A_S;
    const short* qrow = Q + (bS + qs + ln) * ldq + h * A_HD;
    bf16x8 qf[4];
#pragma unroll
    for (int ks = 0; ks < 4; ++ks)
        qf[ks] = *(const bf16x8*)(qrow + ks * 32 + lg * 8);

    f32x4 o[8] = {};
    float lsum[4] = {0.f, 0.f, 0.f, 0.f};

    int C_lo = (Qs - 127) >> 5; if (C_lo < 0) C_lo = 0;
    const int C_hi = (Qs + 63) >> 5;
    const bool sink = C_lo > 0;
    const int total = (C_hi - C_lo + 1) + (sink ? 1 : 0);

    const int key0 = t >> 4, dseg0s = (t & 15) ^ (key0 & 7);
    const int d0 = t >> 2, ksg0 = (t & 3) ^ ((d0 >> 1) & 3);
    const int key1 = (256 + t) >> 4, dseg1s = (t & 15) ^ (key1 & 7);
    const int d1 = (256 + t) >> 2, ksg1 = (t & 3) ^ ((d1 >> 1) & 3);
    const short* Kb = K + bS * A_D + h * A_HD;
    const short* Vb = vT + (size_t)h * A_HD * A_M + b * A_S;

#define ASTAGE(kb, buf)                                                         \
    do {                                                                        \
        gload_lds16(Kb + (size_t)((kb) + key0) * A_D + dseg0s * 8,              \
                    &sK[buf][(size_t)(w * 64) * 8]);                            \
        gload_lds16(Vb + (size_t)d0 * A_M + (kb) + ksg0 * 8,                    \
                    &sV[buf][(size_t)(w * 64) * 8]);                            \
        gload_lds16(Kb + (size_t)((kb) + key1) * A_D + dseg1s * 8,              \
                    &sK[buf][(size_t)(256 + w * 64) * 8]);                      \
        gload_lds16(Vb + (size_t)d1 * A_M + (kb) + ksg1 * 8,                    \
                    &sV[buf][(size_t)(256 + w * 64) * 8]);                      \
    } while (0)

#define CHUNK_KB(ci) ((((sink) && (ci) == 0) ? 0 : (C_lo + (ci) - (sink ? 1 : 0))) * 32)

    ASTAGE(CHUNK_KB(0), 0);
    __syncthreads();

    for (int ci = 0; ci < total; ++ci) {
        if (ci + 1 < total) {
            const int nkb = CHUNK_KB(ci + 1);
            ASTAGE(nkb, (ci + 1) & 1);
        }
        const int kb = CHUNK_KB(ci);
        const int buf = ci & 1;
        const bool any = (kb < 16) || ((kb + 31 >= qs - 127) && (kb <= qs + 15));
        if (any) {
            f32x4 s0 = {0.f, 0.f, 0.f, 0.f}, s1 = {0.f, 0.f, 0.f, 0.f};
#pragma unroll
            for (int ks = 0; ks < 4; ++ks) {
                const int dsg = ks * 4 + lg;
                bf16x8 k0 = *(const bf16x8*)&sK[buf][(ln * 16 + (dsg ^ (ln & 7))) * 8];
                bf16x8 k1 = *(const bf16x8*)&sK[buf][((16 + ln) * 16 + (dsg ^ (ln & 7))) * 8];
                s0 = __builtin_amdgcn_mfma_f32_16x16x32_bf16(qf[ks], k0, s0, 0, 0, 0);
                s1 = __builtin_amdgcn_mfma_f32_16x16x32_bf16(qf[ks], k1, s1, 0, 0, 0);
            }
            const int k0i = kb + ln, k1i = kb + 16 + ln;
#pragma unroll
            for (int r = 0; r < 4; ++r) {
                const int qi = qs + lg * 4 + r;
                const bool m0 = (k0i <= qi) && ((qi - k0i < 128) || (k0i < 16));
                const bool m1 = (k1i <= qi) && ((qi - k1i < 128) || (k1i < 16));
                const float p0 = m0 ? __expf(s0[r] * SCALE) : 0.f;
                const float p1 = m1 ? __expf(s1[r] * SCALE) : 0.f;
                lsum[r] += p0 + p1;
                sP[w][lg * 4 + r][ln] = f2bf(p0);
                sP[w][lg * 4 + r][16 + ln] = f2bf(p1);
            }
            bf16x8 pf = *(const bf16x8*)&sP[w][ln][lg * 8];
#pragma unroll
            for (int dgi = 0; dgi < 8; ++dgi) {
                const int d = dgi * 16 + ln;
                bf16x8 vf = *(const bf16x8*)&sV[buf][(d * 4 + (lg ^ ((ln >> 1) & 3))) * 8];
                o[dgi] = __builtin_amdgcn_mfma_f32_16x16x32_bf16(pf, vf, o[dgi], 0, 0, 0);
            }
        }
        __syncthreads();
    }
#undef ASTAGE
#undef CHUNK_KB

#pragma unroll
    for (int r = 0; r < 4; ++r) {
        float s = lsum[r];
        s += __shfl_xor(s, 1); s += __shfl_xor(s, 2);
        s += __shfl_xor(s, 4); s += __shfl_xor(s, 8);
        const float inv = 1.0f / s;
        short* orow = O + (bS + qs + lg * 4 + r) * A_D + h * A_HD + ln;
#pragma unroll
        for (int dgi = 0; dgi < 8; ++dgi)
            orow[dgi * 16] = f2bf(o[dgi][r] * inv);
    }
}

// ---------- host ----------
extern "C" void kernel_launch(void* const* d_in, const int* in_sizes, int n_in,
                              void* d_out, int out_size, void* d_ws, size_t ws_size,
                              hipStream_t stream) {
    (void)in_sizes; (void)n_in; (void)out_size; (void)ws_size;
    const float* x   = (const float*)d_in[0];
    const float* Wq  = (const float*)d_in[1];
    const float* Wkv = (const float*)d_in[2];
    const float* Wk  = (const float*)d_in[3];
    const float* Wv  = (const float*)d_in[4];
    const float* Wo  = (const float*)d_in[5];
    float* out = (float*)d_out;

    const int B = 2, S = 2048, D = 2048, L = 512, H = 16;
    const int M = B * S;       // 4096
    const int NQ = D + L;      // 2560 (fused q|kvl)

    short* p = (short*)d_ws;
    short* xb    = p; p += (size_t)M * D;
    short* WqkvT = p; p += (size_t)NQ * D;
    short* WkT   = p; p += (size_t)D * L;
    short* WvT   = p; p += (size_t)D * L;
    short* WoT   = p; p += (size_t)D * D;
    short* qkv   = p; p += (size_t)M * NQ;
    short* kk    = p; p += (size_t)M * D;
    short* vT    = p; p += (size_t)D * M;
    short* ao    = p; p += (size_t)M * D;

    // dynamic-LDS opt-ins (once; host-side, graph-capture safe)
    static bool attr_done = false;
    if (!attr_done) {
        hipFuncSetAttribute((const void*)&gemm256_kv,
                            hipFuncAttributeMaxDynamicSharedMemorySize, 131072);
        hipFuncSetAttribute((const void*)&gemm_qkv160,
                            hipFuncAttributeMaxDynamicSharedMemorySize, 106496);
        hipFuncSetAttribute((const void*)&gemm_out,
                            hipFuncAttributeMaxDynamicSharedMemorySize, 98304);
        attr_done = true;
    }

    // one prep dispatch: cvt + all transposes
    prep_all<<<19456, 256, 0, stream>>>(x, xb, Wq, Wo, Wk, Wv, Wkv,
                                        WqkvT, WoT, WkT, WvT);
    // qkv GEMM: [4096][2560] = xb * WqkvT^T, BM256xBN160, 256 blocks exact fill
    gemm_qkv160<<<256, 512, 106496, stream>>>(xb, WqkvT, qkv, D, D, D, NQ);
    // fused kk + vT GEMMs (256 blocks, exact fill, 8-phase)
    gemm256_kv<<<256, 512, 131072, stream>>>(qkv + D, WkT, kk, WvT, vT);

    attn_win3<<<dim3(S / 64, H, B), 256, 0, stream>>>(qkv, kk, vT, ao, NQ);

    // out projection: 256 blocks 1D, XCD-swizzled, BM256xBN128 4-slot pipeline
    gemm_out<<<256, 512, 98304, stream>>>(ao, WoT, out, D, D, D, D);
}